// Round 4
// baseline (2147.292 us; speedup 1.0000x reference)
//
#include <hip/hip_runtime.h>
#include <math.h>

#define WIDTH 192
#define KNN 12
#define G 64
#define NCELLS (G * G * G)

// ---------- sorted-12 list of (d,idx) packed as positive doubles ----------
#define CE(a, b) { double _lo = fmin(a, b); double _hi = fmax(a, b); a = _lo; b = _hi; }
#define INSERT12(key) { \
    b11 = fmin(b11, key); \
    CE(b10, b11); CE(b9, b10); CE(b8, b9); CE(b7, b8); CE(b6, b7); \
    CE(b5, b6);  CE(b4, b5); CE(b3, b4); CE(b2, b3); CE(b1, b2); CE(b0, b1); }
#define DECL12 double b0,b1,b2,b3,b4,b5,b6,b7,b8,b9,b10,b11
#define INIT12 { b0=__hiloint2double(0x7F7FFFFF,0);  b1=__hiloint2double(0x7F7FFFFF,1); \
    b2=__hiloint2double(0x7F7FFFFF,2);  b3=__hiloint2double(0x7F7FFFFF,3); \
    b4=__hiloint2double(0x7F7FFFFF,4);  b5=__hiloint2double(0x7F7FFFFF,5); \
    b6=__hiloint2double(0x7F7FFFFF,6);  b7=__hiloint2double(0x7F7FFFFF,7); \
    b8=__hiloint2double(0x7F7FFFFF,8);  b9=__hiloint2double(0x7F7FFFFF,9); \
    b10=__hiloint2double(0x7F7FFFFF,10); b11=__hiloint2double(0x7F7FFFFF,11); }

__device__ inline unsigned encf(float f) {
    unsigned u = __float_as_uint(f);
    return (u & 0x80000000u) ? ~u : (u | 0x80000000u);
}
__device__ inline float decf(unsigned u) {
    return (u & 0x80000000u) ? __uint_as_float(u & 0x7fffffffu) : __uint_as_float(~u);
}
__device__ inline int cellc(float v, float mn, float invh) {
    int c = (int)((v - mn) * invh);
    return min(max(c, 0), G - 1);
}

// ---------------- prep: padded Fourier PE ------------------------------------
__global__ __launch_bounds__(256) void prep_kernel(
    const float* __restrict__ x, const float* __restrict__ B0,
    const float* __restrict__ B1, const float* __restrict__ B2,
    float* __restrict__ pe, int n)
{
    int i = blockIdx.x * 256 + threadIdx.x;
    float x0 = x[i * 3 + 0], x1 = x[i * 3 + 1], x2 = x[i * 3 + 2];
    const float* Bm[3] = {B0, B1, B2};
    float* pr = pe + (size_t)i * 64;
#pragma unroll
    for (int m = 0; m < 3; ++m) {
        const float* B = Bm[m];
#pragma unroll
        for (int k = 0; k < 8; ++k) {
            float arg = x0 * B[k] + x1 * B[8 + k] + x2 * B[16 + k];
            pr[m * 16 + k]     = sinf(arg);
            pr[m * 16 + 8 + k] = cosf(arg);
        }
    }
    pr[48] = x0; pr[49] = x1; pr[50] = x2;
#pragma unroll
    for (int c = 51; c < 64; ++c) pr[c] = 0.0f;
}

// ---------------- precompute: fold z into biases -----------------------------
__global__ __launch_bounds__(256) void precompute_kernel(
    const float* __restrict__ z, const float* __restrict__ Wp, const float* __restrict__ bp,
    const float* __restrict__ Wg, const float* __restrict__ bg,
    const float* __restrict__ Wb, const float* __restrict__ bb,
    float* __restrict__ bias0, float* __restrict__ gammaB, float* __restrict__ betaB)
{
    __shared__ float zs[64];
    int t = threadIdx.x;
    if (t < 64) zs[t] = z[t];
    __syncthreads();
    if (t < WIDTH) {
        float acc = bp[t];
        for (int k = 0; k < 64; ++k) acc += zs[k] * Wp[(51 + k) * WIDTH + t];
        bias0[t] = acc;
        for (int l = 0; l < 4; ++l) {
            float g = bg[l * WIDTH + t];
            float b = bb[l * WIDTH + t];
            for (int k = 0; k < 64; ++k) {
                g += zs[k] * Wg[(l * 64 + k) * WIDTH + t];
                b += zs[k] * Wb[(l * 64 + k) * WIDTH + t];
            }
            gammaB[l * WIDTH + t] = g;
            betaB[l * WIDTH + t] = b;
        }
    }
}

// ---------------- grid build -------------------------------------------------
__global__ __launch_bounds__(64) void init_bbox_kernel(unsigned* __restrict__ bb)
{
    int t = threadIdx.x;
    if (t < 3) bb[t] = 0xFFFFFFFFu;       // running min (encoded)
    else if (t < 6) bb[t] = 0u;           // running max (encoded)
}

__global__ __launch_bounds__(256) void bbox_kernel(
    const float* __restrict__ x, unsigned* __restrict__ bb, int n)
{
    int i = blockIdx.x * 256 + threadIdx.x;
    unsigned emin[3], emax[3];
#pragma unroll
    for (int a = 0; a < 3; ++a) { unsigned e = encf(x[i * 3 + a]); emin[a] = e; emax[a] = e; }
#pragma unroll
    for (int o = 32; o; o >>= 1) {
#pragma unroll
        for (int a = 0; a < 3; ++a) {
            emin[a] = min(emin[a], (unsigned)__shfl_xor((int)emin[a], o, 64));
            emax[a] = max(emax[a], (unsigned)__shfl_xor((int)emax[a], o, 64));
        }
    }
    if ((threadIdx.x & 63) == 0) {
#pragma unroll
        for (int a = 0; a < 3; ++a) {
            atomicMin(&bb[a], emin[a]);
            atomicMax(&bb[3 + a], emax[a]);
        }
    }
}

__global__ __launch_bounds__(256) void hist_kernel(
    const float* __restrict__ x, const unsigned* __restrict__ bb,
    unsigned* __restrict__ counts, int n)
{
    int i = blockIdx.x * 256 + threadIdx.x;
    float mnx = decf(bb[0]), mny = decf(bb[1]), mnz = decf(bb[2]);
    float ivx = (float)G / (decf(bb[3]) - mnx);
    float ivy = (float)G / (decf(bb[4]) - mny);
    float ivz = (float)G / (decf(bb[5]) - mnz);
    int cx = cellc(x[i * 3 + 0], mnx, ivx);
    int cy = cellc(x[i * 3 + 1], mny, ivy);
    int cz = cellc(x[i * 3 + 2], mnz, ivz);
    atomicAdd(&counts[(cz * G + cy) * G + cx], 1u);
}

// scan1: per-block (1024 elems) exclusive scan; block totals out
__global__ __launch_bounds__(256) void scan1_kernel(
    const unsigned* __restrict__ counts, unsigned* __restrict__ offs,
    unsigned* __restrict__ bsums)
{
    __shared__ unsigned s[256];
    int b = blockIdx.x, t = threadIdx.x;
    unsigned base = (unsigned)b * 1024 + t * 4;
    unsigned v[4], sum = 0;
#pragma unroll
    for (int k = 0; k < 4; ++k) { v[k] = counts[base + k]; sum += v[k]; }
    s[t] = sum; __syncthreads();
    for (int off = 1; off < 256; off <<= 1) {
        unsigned xv = (t >= off) ? s[t - off] : 0u;
        __syncthreads();
        s[t] += xv;
        __syncthreads();
    }
    unsigned excl = s[t] - sum;
    if (t == 255) bsums[b] = s[255];
    unsigned run = excl;
#pragma unroll
    for (int k = 0; k < 4; ++k) { offs[base + k] = run; run += v[k]; }
}

__global__ __launch_bounds__(256) void scan2_kernel(unsigned* __restrict__ bsums)
{
    __shared__ unsigned s[256];
    int t = threadIdx.x;
    unsigned v = bsums[t];
    s[t] = v; __syncthreads();
    for (int off = 1; off < 256; off <<= 1) {
        unsigned xv = (t >= off) ? s[t - off] : 0u;
        __syncthreads();
        s[t] += xv;
        __syncthreads();
    }
    bsums[t] = s[t] - v;   // exclusive
}

__global__ __launch_bounds__(256) void scan3_kernel(
    unsigned* __restrict__ offs, const unsigned* __restrict__ bsums,
    unsigned* __restrict__ cursors, int n)
{
    int b = blockIdx.x, t = threadIdx.x;
    unsigned add = bsums[b];
    unsigned base = (unsigned)b * 1024 + t * 4;
#pragma unroll
    for (int k = 0; k < 4; ++k) {
        unsigned v = offs[base + k] + add;
        offs[base + k] = v;
        cursors[base + k] = v;
    }
    if (b == 255 && t == 255) offs[NCELLS] = (unsigned)n;
}

__global__ __launch_bounds__(256) void scatter_kernel(
    const float* __restrict__ x, const unsigned* __restrict__ bb,
    unsigned* __restrict__ cursors, float4* __restrict__ sorted, int n)
{
    int i = blockIdx.x * 256 + threadIdx.x;
    float mnx = decf(bb[0]), mny = decf(bb[1]), mnz = decf(bb[2]);
    float ivx = (float)G / (decf(bb[3]) - mnx);
    float ivy = (float)G / (decf(bb[4]) - mny);
    float ivz = (float)G / (decf(bb[5]) - mnz);
    float x0 = x[i * 3 + 0], x1 = x[i * 3 + 1], x2 = x[i * 3 + 2];
    int cx = cellc(x0, mnx, ivx);
    int cy = cellc(x1, mny, ivy);
    int cz = cellc(x2, mnz, ivz);
    unsigned pos = atomicAdd(&cursors[(cz * G + cy) * G + cx], 1u);
    sorted[pos] = make_float4(x0, x1, x2, __int_as_float(i));
}

// ---------------- grid kNN search + rel_feat ---------------------------------
__global__ __launch_bounds__(256) void knn_grid_kernel(
    const float4* __restrict__ sorted, const unsigned* __restrict__ offs,
    const unsigned* __restrict__ bb, const float* __restrict__ x,
    unsigned short* __restrict__ knn, float* __restrict__ relf, int n)
{
    int p = blockIdx.x * 256 + threadIdx.x;
    float mnx = decf(bb[0]), mny = decf(bb[1]), mnz = decf(bb[2]);
    float mxx = decf(bb[3]), mxy = decf(bb[4]), mxz = decf(bb[5]);
    float hx = (mxx - mnx) / G, hy = (mxy - mny) / G, hz = (mxz - mnz) / G;
    float ivx = (float)G / (mxx - mnx);
    float ivy = (float)G / (mxy - mny);
    float ivz = (float)G / (mxz - mnz);

    float4 q = sorted[p];
    float xi = q.x, yi = q.y, zi = q.z;
    int iorig = __float_as_int(q.w);
    float sqi = fmaf(zi, zi, fmaf(yi, yi, xi * xi));
    int cx = cellc(xi, mnx, ivx), cy = cellc(yi, mny, ivy), cz = cellc(zi, mnz, ivz);
    float fx = (xi - mnx) - cx * hx;
    float fy = (yi - mny) - cy * hy;
    float fz = (zi - mnz) - cz * hz;

    DECL12; INIT12;
    float worst = 3.402823466e+38f;

    auto scanRange = [&](int c0, int c1) {
        unsigned j0 = offs[c0], j1 = offs[c1 + 1];
        for (unsigned t = j0; t < j1; ++t) {
            float4 c = sorted[t];
            float sqj = fmaf(c.z, c.z, fmaf(c.y, c.y, c.x * c.x));
            float dot = fmaf(zi, c.z, fmaf(yi, c.y, xi * c.x));
            float d = fmaf(-2.0f, dot, sqi + sqj);
            int jg = __float_as_int(c.w);
            if (d <= worst && jg != iorig) {
                d = fmaxf(d, 0.0f);
                double key = __hiloint2double(__float_as_int(d), jg);
                INSERT12(key);
                worst = __int_as_float(__double2hiint(b11));
            }
        }
    };

    for (int s = 0; s < G; ++s) {
        if (s > 0) {
            float bx = (s - 1) * hx + fminf(fx, hx - fx);
            float by = (s - 1) * hy + fminf(fy, hy - fy);
            float bz = (s - 1) * hz + fminf(fz, hz - fz);
            float bnd = fminf(bx, fminf(by, bz));
            if (bnd * bnd > worst + 1e-4f) break;   // margin >> fp error of d-formula
        }
        int z0 = max(cz - s, 0), z1 = min(cz + s, G - 1);
        for (int cz2 = z0; cz2 <= z1; ++cz2) {
            int adz = cz2 > cz ? cz2 - cz : cz - cz2;
            int y0 = max(cy - s, 0), y1 = min(cy + s, G - 1);
            for (int cy2 = y0; cy2 <= y1; ++cy2) {
                int ady = cy2 > cy ? cy2 - cy : cy - cy2;
                int rb = (cz2 * G + cy2) * G;
                if (s == 0 || adz == s || ady == s) {
                    scanRange(rb + max(cx - s, 0), rb + min(cx + s, G - 1));
                } else {
                    int xm = cx - s, xp = cx + s;
                    if (xm >= 0) scanRange(rb + xm, rb + xm);
                    if (xp < G)  scanRange(rb + xp, rb + xp);
                }
            }
        }
    }

    int idx[KNN];
    idx[0]=__double2loint(b0);  idx[1]=__double2loint(b1);  idx[2]=__double2loint(b2);
    idx[3]=__double2loint(b3);  idx[4]=__double2loint(b4);  idx[5]=__double2loint(b5);
    idx[6]=__double2loint(b6);  idx[7]=__double2loint(b7);  idx[8]=__double2loint(b8);
    idx[9]=__double2loint(b9);  idx[10]=__double2loint(b10); idx[11]=__double2loint(b11);

    float rx[KNN], ry[KNN], rz[KNN];
    float sx = 0.f, sy = 0.f, sz = 0.f;
#pragma unroll
    for (int s = 0; s < KNN; ++s) {
        int j = idx[s];
        knn[(size_t)iorig * KNN + s] = (unsigned short)j;
        rx[s] = x[(size_t)j * 3 + 0] - xi;
        ry[s] = x[(size_t)j * 3 + 1] - yi;
        rz[s] = x[(size_t)j * 3 + 2] - zi;
        sx += rx[s]; sy += ry[s]; sz += rz[s];
    }
    float mx = sx / 12.0f, my = sy / 12.0f, mz = sz / 12.0f;
    float vx = 0.f, vy = 0.f, vz = 0.f;
#pragma unroll
    for (int s = 0; s < KNN; ++s) {
        float dx = rx[s] - mx, dy = ry[s] - my, dz = rz[s] - mz;
        vx += dx * dx; vy += dy * dy; vz += dz * dz;
    }
    float* rr = relf + (size_t)iorig * 8;
    rr[0] = mx; rr[1] = my; rr[2] = mz;
    rr[3] = sqrtf(vx / 12.0f); rr[4] = sqrtf(vy / 12.0f); rr[5] = sqrtf(vz / 12.0f);
    rr[6] = 0.0f; rr[7] = 0.0f;
}

// ---------------- GEMM + silu (+FiLM): 128x192 tile, 8x12 micro --------------
template <bool LAYER>
__global__ __launch_bounds__(256) void gemm_silu_kernel(
    const float* __restrict__ A0, const float* __restrict__ Agg,
    const float* __restrict__ Rel,
    const float* __restrict__ W, const float* __restrict__ bias,
    const float* __restrict__ gamma, const float* __restrict__ beta,
    float* __restrict__ out)
{
    __shared__ float As[16][132];
    __shared__ float Bs[16][196];
    const int tid = threadIdx.x;
    const int ty = tid >> 4, tx = tid & 15;
    const int m0 = blockIdx.x * 128;

    float acc[8][12] = {};

    const int NCH = LAYER ? 24 : 4;
    for (int ch = 0; ch < NCH; ++ch) {
        const int k0 = ch * 16;
        {
            int row = tid >> 1, koff = (tid & 1) * 8;
            int gi = m0 + row;
            const float* src; int stride, col;
            if (!LAYER)            { src = A0;  stride = 64;  col = k0 + koff; }
            else if (k0 < 192)     { src = A0;  stride = 192; col = k0 + koff; }
            else                   { src = Agg; stride = 192; col = k0 - 192 + koff; }
            float4 v0 = *(const float4*)&src[(size_t)gi * stride + col];
            float4 v1 = *(const float4*)&src[(size_t)gi * stride + col + 4];
            As[koff + 0][row] = v0.x; As[koff + 1][row] = v0.y;
            As[koff + 2][row] = v0.z; As[koff + 3][row] = v0.w;
            As[koff + 4][row] = v1.x; As[koff + 5][row] = v1.y;
            As[koff + 6][row] = v1.z; As[koff + 7][row] = v1.w;
        }
        {
            int k2 = tid >> 4, c = (tid & 15) * 12;
            const float* wr = &W[(size_t)(k0 + k2) * 192 + c];
            float4 w0 = *(const float4*)&wr[0];
            float4 w1 = *(const float4*)&wr[4];
            float4 w2 = *(const float4*)&wr[8];
            *(float4*)&Bs[k2][c + 0] = w0;
            *(float4*)&Bs[k2][c + 4] = w1;
            *(float4*)&Bs[k2][c + 8] = w2;
        }
        __syncthreads();
#pragma unroll
        for (int k = 0; k < 16; ++k) {
            float4 a0 = *(const float4*)&As[k][ty * 8 + 0];
            float4 a1 = *(const float4*)&As[k][ty * 8 + 4];
            float av[8] = {a0.x, a0.y, a0.z, a0.w, a1.x, a1.y, a1.z, a1.w};
            float4 q0 = *(const float4*)&Bs[k][tx * 12 + 0];
            float4 q1 = *(const float4*)&Bs[k][tx * 12 + 4];
            float4 q2 = *(const float4*)&Bs[k][tx * 12 + 8];
            float bv[12] = {q0.x, q0.y, q0.z, q0.w, q1.x, q1.y, q1.z, q1.w,
                            q2.x, q2.y, q2.z, q2.w};
#pragma unroll
            for (int a = 0; a < 8; ++a)
#pragma unroll
                for (int b = 0; b < 12; ++b)
                    acc[a][b] = fmaf(av[a], bv[b], acc[a][b]);
        }
        __syncthreads();
    }

    if (LAYER) {
        {
            int row = tid >> 1, col = (tid & 1) * 4;
            float4 v = *(const float4*)&Rel[(size_t)(m0 + row) * 8 + col];
            As[col + 0][row] = v.x; As[col + 1][row] = v.y;
            As[col + 2][row] = v.z; As[col + 3][row] = v.w;
        }
        {
            int k2 = tid >> 4, c = (tid & 15) * 12;
            if (k2 < 8) {
                int gk = 384 + k2; if (gk > 389) gk = 389;
                const float* wr = &W[(size_t)gk * 192 + c];
                float4 w0 = *(const float4*)&wr[0];
                float4 w1 = *(const float4*)&wr[4];
                float4 w2 = *(const float4*)&wr[8];
                *(float4*)&Bs[k2][c + 0] = w0;
                *(float4*)&Bs[k2][c + 4] = w1;
                *(float4*)&Bs[k2][c + 8] = w2;
            }
        }
        __syncthreads();
#pragma unroll
        for (int k = 0; k < 8; ++k) {
            float4 a0 = *(const float4*)&As[k][ty * 8 + 0];
            float4 a1 = *(const float4*)&As[k][ty * 8 + 4];
            float av[8] = {a0.x, a0.y, a0.z, a0.w, a1.x, a1.y, a1.z, a1.w};
            float4 q0 = *(const float4*)&Bs[k][tx * 12 + 0];
            float4 q1 = *(const float4*)&Bs[k][tx * 12 + 4];
            float4 q2 = *(const float4*)&Bs[k][tx * 12 + 8];
            float bv[12] = {q0.x, q0.y, q0.z, q0.w, q1.x, q1.y, q1.z, q1.w,
                            q2.x, q2.y, q2.z, q2.w};
#pragma unroll
            for (int a = 0; a < 8; ++a)
#pragma unroll
                for (int b = 0; b < 12; ++b)
                    acc[a][b] = fmaf(av[a], bv[b], acc[a][b]);
        }
        __syncthreads();
    }

#pragma unroll
    for (int a = 0; a < 8; ++a) {
        int gi = m0 + ty * 8 + a;
        float res[12];
#pragma unroll
        for (int b = 0; b < 12; ++b) {
            int gc = tx * 12 + b;
            float v = acc[a][b] + bias[gc];
            float s = 1.0f / (1.0f + expf(-v));
            v = v * s;
            if (LAYER) v = v * gamma[gc] + beta[gc];
            res[b] = v;
        }
        float* orow = &out[(size_t)gi * 192 + tx * 12];
        *(float4*)&orow[0] = make_float4(res[0], res[1], res[2], res[3]);
        *(float4*)&orow[4] = make_float4(res[4], res[5], res[6], res[7]);
        *(float4*)&orow[8] = make_float4(res[8], res[9], res[10], res[11]);
    }
}

// ---------------- neighbor aggregation (float4) ------------------------------
__global__ __launch_bounds__(256) void agg_kernel(
    const float4* __restrict__ h4, const unsigned short* __restrict__ knn,
    float4* __restrict__ agg4, int n)
{
    int flat = blockIdx.x * 256 + threadIdx.x;
    int i = flat / 48;
    int c4 = flat - i * 48;
    const unsigned short* kn = knn + (size_t)i * KNN;
    float4 s = make_float4(0.f, 0.f, 0.f, 0.f);
#pragma unroll
    for (int j = 0; j < KNN; ++j) {
        float4 v = h4[(size_t)kn[j] * 48 + c4];
        s.x += v.x; s.y += v.y; s.z += v.z; s.w += v.w;
    }
    const float r = 1.0f / 12.0f;
    agg4[flat] = make_float4(s.x * r, s.y * r, s.z * r, s.w * r);
}

// ---------------- output head ------------------------------------------------
__global__ __launch_bounds__(256) void out_kernel(
    const float4* __restrict__ h4, const float* __restrict__ Wout,
    const float* __restrict__ bout, float* __restrict__ out, int n)
{
    __shared__ float w[576];
    int t = threadIdx.x;
    for (int e = t; e < 576; e += 256) w[e] = Wout[e];
    __syncthreads();
    int i = blockIdx.x * 256 + t;
    float a0 = 0.f, a1 = 0.f, a2 = 0.f;
    for (int k4 = 0; k4 < 48; ++k4) {
        float4 hv = h4[(size_t)i * 48 + k4];
        int k = k4 * 4;
        a0 = fmaf(hv.x, w[k * 3 + 0], a0); a1 = fmaf(hv.x, w[k * 3 + 1], a1); a2 = fmaf(hv.x, w[k * 3 + 2], a2);
        a0 = fmaf(hv.y, w[k * 3 + 3], a0); a1 = fmaf(hv.y, w[k * 3 + 4], a1); a2 = fmaf(hv.y, w[k * 3 + 5], a2);
        a0 = fmaf(hv.z, w[k * 3 + 6], a0); a1 = fmaf(hv.z, w[k * 3 + 7], a1); a2 = fmaf(hv.z, w[k * 3 + 8], a2);
        a0 = fmaf(hv.w, w[k * 3 + 9], a0); a1 = fmaf(hv.w, w[k * 3 + 10], a1); a2 = fmaf(hv.w, w[k * 3 + 11], a2);
    }
    out[(size_t)i * 3 + 0] = (a0 + bout[0]) * 0.01f;
    out[(size_t)i * 3 + 1] = (a1 + bout[1]) * 0.01f;
    out[(size_t)i * 3 + 2] = (a2 + bout[2]) * 0.01f;
}

// ---------------- launch ------------------------------------------------------
extern "C" void kernel_launch(void* const* d_in, const int* in_sizes, int n_in,
                              void* d_out, int out_size, void* d_ws, size_t ws_size,
                              hipStream_t stream)
{
    const float* x    = (const float*)d_in[0];
    const float* z    = (const float*)d_in[1];
    const float* B0   = (const float*)d_in[2];
    const float* B1   = (const float*)d_in[3];
    const float* B2   = (const float*)d_in[4];
    const float* Wp   = (const float*)d_in[5];
    const float* bp   = (const float*)d_in[6];
    const float* Wl   = (const float*)d_in[7];
    const float* bl   = (const float*)d_in[8];
    const float* Wg   = (const float*)d_in[9];
    const float* bg   = (const float*)d_in[10];
    const float* Wb   = (const float*)d_in[11];
    const float* bb   = (const float*)d_in[12];
    const float* Wout = (const float*)d_in[13];
    const float* bout = (const float*)d_in[14];

    int n = in_sizes[0] / 3;  // 32768

    // workspace layout (float offsets)
    float* ws = (float*)d_ws;
    float* bias0  = ws;                    // 192
    float* gammaB = ws + 192;              // 768
    float* betaB  = ws + 960;              // 768
    size_t off = 1728;
    unsigned short* knn = (unsigned short*)(ws + off);  off += (size_t)n * 6;  // 12n u16
    float* relf = ws + off;                off += (size_t)n * 8;
    float* hA   = ws + off;                off += (size_t)n * 192;
    float* hB   = ws + off;                off += (size_t)n * 192;
    float* aggb = ws + off;                off += (size_t)n * 192;

    // grid scratch aliases inside hA (dead before gemm0 writes hA):
    unsigned* bbx     = (unsigned*)hA;              // 8 (6 used)
    unsigned* counts  = bbx + 8;                    // NCELLS
    unsigned* offsA   = counts + NCELLS;            // NCELLS + 1
    unsigned* cursors = offsA + NCELLS + 1;         // NCELLS
    unsigned* bsums   = cursors + NCELLS;           // 256
    size_t gu = 8 + (size_t)NCELLS * 3 + 1 + 256;
    gu = (gu + 3) & ~(size_t)3;                     // 16B align for float4
    float4* sorted = (float4*)((unsigned*)hA + gu); // n float4
    // pe aliases hB (dead after gemm0 reads it)
    float* pe = hB;

    init_bbox_kernel<<<1, 64, 0, stream>>>(bbx);
    hipMemsetAsync(counts, 0, (size_t)NCELLS * 4, stream);
    prep_kernel<<<n / 256, 256, 0, stream>>>(x, B0, B1, B2, pe, n);
    precompute_kernel<<<1, 256, 0, stream>>>(z, Wp, bp, Wg, bg, Wb, bb,
                                             bias0, gammaB, betaB);
    bbox_kernel<<<n / 256, 256, 0, stream>>>(x, bbx, n);
    hist_kernel<<<n / 256, 256, 0, stream>>>(x, bbx, counts, n);
    scan1_kernel<<<NCELLS / 1024, 256, 0, stream>>>(counts, offsA, bsums);
    scan2_kernel<<<1, 256, 0, stream>>>(bsums);
    scan3_kernel<<<NCELLS / 1024, 256, 0, stream>>>(offsA, bsums, cursors, n);
    scatter_kernel<<<n / 256, 256, 0, stream>>>(x, bbx, cursors, sorted, n);
    knn_grid_kernel<<<n / 256, 256, 0, stream>>>(sorted, offsA, bbx, x, knn, relf, n);

    // h0 = silu(pe @ Wp[:64] + bias0) -> hA
    gemm_silu_kernel<false><<<n / 128, 256, 0, stream>>>(
        pe, nullptr, nullptr, Wp, bias0, nullptr, nullptr, hA);

    float* hcur = hA;
    float* hnxt = hB;
    for (int li = 0; li < 4; ++li) {
        agg_kernel<<<(size_t)n * 48 / 256, 256, 0, stream>>>(
            (const float4*)hcur, knn, (float4*)aggb, n);
        gemm_silu_kernel<true><<<n / 128, 256, 0, stream>>>(
            hcur, aggb, relf,
            Wl + (size_t)li * 390 * 192, bl + (size_t)li * 192,
            gammaB + (size_t)li * 192, betaB + (size_t)li * 192, hnxt);
        float* t = hcur; hcur = hnxt; hnxt = t;
    }

    out_kernel<<<n / 256, 256, 0, stream>>>((const float4*)hcur, Wout, bout,
                                            (float*)d_out, n);
}

// Round 6
// 1252.730 us; speedup vs baseline: 1.7141x; 1.7141x over previous
//
#include <hip/hip_runtime.h>
#include <math.h>

#define WIDTH 192
#define KNN 12
#define G 64
#define NCELLS (G * G * G)

// ---------- sorted-12 list of (d,idx) packed as positive doubles ----------
#define CE(a, b) { double _lo = fmin(a, b); double _hi = fmax(a, b); a = _lo; b = _hi; }
#define INSERT12(key) { \
    b11 = fmin(b11, key); \
    CE(b10, b11); CE(b9, b10); CE(b8, b9); CE(b7, b8); CE(b6, b7); \
    CE(b5, b6);  CE(b4, b5); CE(b3, b4); CE(b2, b3); CE(b1, b2); CE(b0, b1); }
#define DECL12 double b0,b1,b2,b3,b4,b5,b6,b7,b8,b9,b10,b11
#define INIT12 { b0=__hiloint2double(0x7F7FFFFF,0);  b1=__hiloint2double(0x7F7FFFFF,1); \
    b2=__hiloint2double(0x7F7FFFFF,2);  b3=__hiloint2double(0x7F7FFFFF,3); \
    b4=__hiloint2double(0x7F7FFFFF,4);  b5=__hiloint2double(0x7F7FFFFF,5); \
    b6=__hiloint2double(0x7F7FFFFF,6);  b7=__hiloint2double(0x7F7FFFFF,7); \
    b8=__hiloint2double(0x7F7FFFFF,8);  b9=__hiloint2double(0x7F7FFFFF,9); \
    b10=__hiloint2double(0x7F7FFFFF,10); b11=__hiloint2double(0x7F7FFFFF,11); }

__device__ inline unsigned encf(float f) {
    unsigned u = __float_as_uint(f);
    return (u & 0x80000000u) ? ~u : (u | 0x80000000u);
}
__device__ inline float decf(unsigned u) {
    return (u & 0x80000000u) ? __uint_as_float(u & 0x7fffffffu) : __uint_as_float(~u);
}
__device__ inline int cellc(float v, float mn, float invh) {
    int c = (int)((v - mn) * invh);
    return min(max(c, 0), G - 1);
}
__device__ inline double shflx_d(double v, int m) {
    int lo = __shfl_xor(__double2loint(v), m, 64);
    int hi = __shfl_xor(__double2hiint(v), m, 64);
    return __hiloint2double(hi, lo);
}

// ---------------- prep: padded Fourier PE ------------------------------------
__global__ __launch_bounds__(256) void prep_kernel(
    const float* __restrict__ x, const float* __restrict__ B0,
    const float* __restrict__ B1, const float* __restrict__ B2,
    float* __restrict__ pe, int n)
{
    int i = blockIdx.x * 256 + threadIdx.x;
    float x0 = x[i * 3 + 0], x1 = x[i * 3 + 1], x2 = x[i * 3 + 2];
    const float* Bm[3] = {B0, B1, B2};
    float* pr = pe + (size_t)i * 64;
#pragma unroll
    for (int m = 0; m < 3; ++m) {
        const float* B = Bm[m];
#pragma unroll
        for (int k = 0; k < 8; ++k) {
            float arg = x0 * B[k] + x1 * B[8 + k] + x2 * B[16 + k];
            pr[m * 16 + k]     = sinf(arg);
            pr[m * 16 + 8 + k] = cosf(arg);
        }
    }
    pr[48] = x0; pr[49] = x1; pr[50] = x2;
#pragma unroll
    for (int c = 51; c < 64; ++c) pr[c] = 0.0f;
}

// ---------------- precompute: fold z into biases -----------------------------
__global__ __launch_bounds__(256) void precompute_kernel(
    const float* __restrict__ z, const float* __restrict__ Wp, const float* __restrict__ bp,
    const float* __restrict__ Wg, const float* __restrict__ bg,
    const float* __restrict__ Wb, const float* __restrict__ bb,
    float* __restrict__ bias0, float* __restrict__ gammaB, float* __restrict__ betaB)
{
    __shared__ float zs[64];
    int t = threadIdx.x;
    if (t < 64) zs[t] = z[t];
    __syncthreads();
    if (t < WIDTH) {
        float acc = bp[t];
        for (int k = 0; k < 64; ++k) acc += zs[k] * Wp[(51 + k) * WIDTH + t];
        bias0[t] = acc;
        for (int l = 0; l < 4; ++l) {
            float g = bg[l * WIDTH + t];
            float b = bb[l * WIDTH + t];
            for (int k = 0; k < 64; ++k) {
                g += zs[k] * Wg[(l * 64 + k) * WIDTH + t];
                b += zs[k] * Wb[(l * 64 + k) * WIDTH + t];
            }
            gammaB[l * WIDTH + t] = g;
            betaB[l * WIDTH + t] = b;
        }
    }
}

// ---------------- grid build -------------------------------------------------
__global__ __launch_bounds__(64) void init_bbox_kernel(unsigned* __restrict__ bb)
{
    int t = threadIdx.x;
    if (t < 3) bb[t] = 0xFFFFFFFFu;
    else if (t < 6) bb[t] = 0u;
}

__global__ __launch_bounds__(256) void bbox_kernel(
    const float* __restrict__ x, unsigned* __restrict__ bb, int n)
{
    int i = blockIdx.x * 256 + threadIdx.x;
    unsigned emin[3], emax[3];
#pragma unroll
    for (int a = 0; a < 3; ++a) { unsigned e = encf(x[i * 3 + a]); emin[a] = e; emax[a] = e; }
#pragma unroll
    for (int o = 32; o; o >>= 1) {
#pragma unroll
        for (int a = 0; a < 3; ++a) {
            emin[a] = min(emin[a], (unsigned)__shfl_xor((int)emin[a], o, 64));
            emax[a] = max(emax[a], (unsigned)__shfl_xor((int)emax[a], o, 64));
        }
    }
    if ((threadIdx.x & 63) == 0) {
#pragma unroll
        for (int a = 0; a < 3; ++a) {
            atomicMin(&bb[a], emin[a]);
            atomicMax(&bb[3 + a], emax[a]);
        }
    }
}

__global__ __launch_bounds__(256) void hist_kernel(
    const float* __restrict__ x, const unsigned* __restrict__ bb,
    unsigned* __restrict__ counts, int n)
{
    int i = blockIdx.x * 256 + threadIdx.x;
    float mnx = decf(bb[0]), mny = decf(bb[1]), mnz = decf(bb[2]);
    float ivx = (float)G / (decf(bb[3]) - mnx);
    float ivy = (float)G / (decf(bb[4]) - mny);
    float ivz = (float)G / (decf(bb[5]) - mnz);
    int cx = cellc(x[i * 3 + 0], mnx, ivx);
    int cy = cellc(x[i * 3 + 1], mny, ivy);
    int cz = cellc(x[i * 3 + 2], mnz, ivz);
    atomicAdd(&counts[(cz * G + cy) * G + cx], 1u);
}

__global__ __launch_bounds__(256) void scan1_kernel(
    const unsigned* __restrict__ counts, unsigned* __restrict__ offs,
    unsigned* __restrict__ bsums)
{
    __shared__ unsigned s[256];
    int b = blockIdx.x, t = threadIdx.x;
    unsigned base = (unsigned)b * 1024 + t * 4;
    unsigned v[4], sum = 0;
#pragma unroll
    for (int k = 0; k < 4; ++k) { v[k] = counts[base + k]; sum += v[k]; }
    s[t] = sum; __syncthreads();
    for (int off = 1; off < 256; off <<= 1) {
        unsigned xv = (t >= off) ? s[t - off] : 0u;
        __syncthreads();
        s[t] += xv;
        __syncthreads();
    }
    unsigned excl = s[t] - sum;
    if (t == 255) bsums[b] = s[255];
    unsigned run = excl;
#pragma unroll
    for (int k = 0; k < 4; ++k) { offs[base + k] = run; run += v[k]; }
}

__global__ __launch_bounds__(256) void scan2_kernel(unsigned* __restrict__ bsums)
{
    __shared__ unsigned s[256];
    int t = threadIdx.x;
    unsigned v = bsums[t];
    s[t] = v; __syncthreads();
    for (int off = 1; off < 256; off <<= 1) {
        unsigned xv = (t >= off) ? s[t - off] : 0u;
        __syncthreads();
        s[t] += xv;
        __syncthreads();
    }
    bsums[t] = s[t] - v;
}

__global__ __launch_bounds__(256) void scan3_kernel(
    unsigned* __restrict__ offs, const unsigned* __restrict__ bsums,
    unsigned* __restrict__ cursors, int n)
{
    int b = blockIdx.x, t = threadIdx.x;
    unsigned add = bsums[b];
    unsigned base = (unsigned)b * 1024 + t * 4;
#pragma unroll
    for (int k = 0; k < 4; ++k) {
        unsigned v = offs[base + k] + add;
        offs[base + k] = v;
        cursors[base + k] = v;
    }
    if (b == 255 && t == 255) offs[NCELLS] = (unsigned)n;
}

__global__ __launch_bounds__(256) void scatter_kernel(
    const float* __restrict__ x, const unsigned* __restrict__ bb,
    unsigned* __restrict__ cursors, float4* __restrict__ sorted, int n)
{
    int i = blockIdx.x * 256 + threadIdx.x;
    float mnx = decf(bb[0]), mny = decf(bb[1]), mnz = decf(bb[2]);
    float ivx = (float)G / (decf(bb[3]) - mnx);
    float ivy = (float)G / (decf(bb[4]) - mny);
    float ivz = (float)G / (decf(bb[5]) - mnz);
    float x0 = x[i * 3 + 0], x1 = x[i * 3 + 1], x2 = x[i * 3 + 2];
    int cx = cellc(x0, mnx, ivx);
    int cy = cellc(x1, mny, ivy);
    int cz = cellc(x2, mnz, ivz);
    unsigned pos = atomicAdd(&cursors[(cz * G + cy) * G + cx], 1u);
    sorted[pos] = make_float4(x0, x1, x2, __int_as_float(i));
}

// ---------------- grid kNN: 16 lanes per query, ring search ------------------
__global__ __launch_bounds__(256) void knn_grid_kernel(
    const float4* __restrict__ sorted, const unsigned* __restrict__ offs,
    const unsigned* __restrict__ bb, const float* __restrict__ x,
    unsigned short* __restrict__ knn, float* __restrict__ relf, int n)
{
    const int tid = threadIdx.x;
    const int l = tid & 15;                  // lane in group
    const int grp = tid >> 4;                // group in block (16 groups)
    const int p = blockIdx.x * 16 + grp;     // query = sorted index

    float mnx = decf(bb[0]), mny = decf(bb[1]), mnz = decf(bb[2]);
    float mxx = decf(bb[3]), mxy = decf(bb[4]), mxz = decf(bb[5]);
    float hx = (mxx - mnx) / G, hy = (mxy - mny) / G, hz = (mxz - mnz) / G;
    float ivx = (float)G / (mxx - mnx);
    float ivy = (float)G / (mxy - mny);
    float ivz = (float)G / (mxz - mnz);

    float4 q = sorted[p];
    float xi = q.x, yi = q.y, zi = q.z;
    int iorig = __float_as_int(q.w);
    float sqi = fmaf(zi, zi, fmaf(yi, yi, xi * xi));
    int cx = cellc(xi, mnx, ivx), cy = cellc(yi, mny, ivy), cz = cellc(zi, mnz, ivz);
    float fx = (xi - mnx) - cx * hx;
    float fy = (yi - mny) - cy * hy;
    float fz = (zi - mnz) - cz * hz;

    DECL12; INIT12;
    float worst = 3.402823466e+38f;    // this lane's 12th-best distance
    float worst_g = 3.402823466e+38f;  // group-min (upper bound on true d12)

    auto scanRange = [&](int c0, int c1) {
        unsigned j0 = offs[c0], j1 = offs[c1 + 1];
        for (unsigned t = j0; t < j1; ++t) {
            float4 c = sorted[t];
            float sqj = fmaf(c.z, c.z, fmaf(c.y, c.y, c.x * c.x));
            float dot = fmaf(zi, c.z, fmaf(yi, c.y, xi * c.x));
            float d = fmaf(-2.0f, dot, sqi + sqj);
            int jg = __float_as_int(c.w);
            if (d <= fminf(worst, worst_g) && jg != iorig) {
                d = fmaxf(d, 0.0f);
                double key = __hiloint2double(__float_as_int(d), jg);
                INSERT12(key);
                worst = __int_as_float(__double2hiint(b11));
            }
        }
    };

    for (int s = 0; s < G; ++s) {
        // group-min of lane worsts (valid upper bound on true 12th distance)
        {
            float wm = worst;
            wm = fminf(wm, __shfl_xor(wm, 1, 64));
            wm = fminf(wm, __shfl_xor(wm, 2, 64));
            wm = fminf(wm, __shfl_xor(wm, 4, 64));
            wm = fminf(wm, __shfl_xor(wm, 8, 64));
            worst_g = wm;
        }
        if (s > 0) {
            float bx = (s - 1) * hx + fminf(fx, hx - fx);
            float by = (s - 1) * hy + fminf(fy, hy - fy);
            float bz = (s - 1) * hz + fminf(fz, hz - fz);
            float bnd = fminf(bx, fminf(by, bz));
            if (bnd * bnd > worst_g + 1e-4f) break;  // margin >> fp error of d
        }
        if (s == 0) {
            if (l == 0) {
                int rb = (cz * G + cy) * G;
                scanRange(rb + cx, rb + cx);
            }
        } else {
            int w2 = 2 * s + 1;
            float rcp = 1.0f / (float)w2;
            int nrows = w2 * w2;
            for (int r = l; r < nrows; r += 16) {
                int qd = (int)((float)r * rcp);
                int rem = r - qd * w2;
                if (rem < 0) { qd--; rem += w2; }
                else if (rem >= w2) { qd++; rem -= w2; }
                int dz = qd - s, dy = rem - s;
                int zz = cz + dz, yy = cy + dy;
                if (zz < 0 || zz >= G || yy < 0 || yy >= G) continue;
                int rb = (zz * G + yy) * G;
                int adz = dz < 0 ? -dz : dz, ady = dy < 0 ? -dy : dy;
                if (adz == s || ady == s) {
                    scanRange(rb + max(cx - s, 0), rb + min(cx + s, G - 1));
                } else {
                    if (cx - s >= 0) scanRange(rb + cx - s, rb + cx - s);
                    if (cx + s < G)  scanRange(rb + cx + s, rb + cx + s);
                }
            }
        }
    }

    // ---- exact merge of 16 sorted-12 lists (butterfly, virtual length-16
    //      lists padded with +inf, half-cleaner + full Batcher BM16) ----
#pragma unroll
    for (int m = 1; m <= 8; m <<= 1) {
        double pb11 = shflx_d(b11, m), pb10 = shflx_d(b10, m), pb9 = shflx_d(b9, m);
        double pb8  = shflx_d(b8, m),  pb7  = shflx_d(b7, m),  pb6 = shflx_d(b6, m);
        double pb5  = shflx_d(b5, m),  pb4  = shflx_d(b4, m),  pb3 = shflx_d(b3, m);
        double pb2  = shflx_d(b2, m),  pb1  = shflx_d(b1, m),  pb0 = shflx_d(b0, m);
        // half-cleaner of [a0..a15 | b15..b0] with a12..a15 = +inf:
        //   c_i = min(a_i, partner_b_{15-i});  c0..3 = a0..3 (partner pads = inf)
        double c12 = pb3, c13 = pb2, c14 = pb1, c15 = pb0;
        b4 = fmin(b4, pb11); b5 = fmin(b5, pb10); b6 = fmin(b6, pb9);  b7 = fmin(b7, pb8);
        b8 = fmin(b8, pb7);  b9 = fmin(b9, pb6);  b10 = fmin(b10, pb5); b11 = fmin(b11, pb4);
        // BM16 cleanup of the (bitonic) lower half
        CE(b0, b8);  CE(b1, b9);  CE(b2, b10); CE(b3, b11);
        CE(b4, c12); CE(b5, c13); CE(b6, c14); CE(b7, c15);
        CE(b0, b4);  CE(b1, b5);  CE(b2, b6);  CE(b3, b7);
        CE(b8, c12); CE(b9, c13); CE(b10, c14); CE(b11, c15);
        CE(b0, b2);  CE(b1, b3);  CE(b4, b6);  CE(b5, b7);
        CE(b8, b10); CE(b9, b11);
        CE(b0, b1);  CE(b2, b3);  CE(b4, b5);  CE(b6, b7);
        CE(b8, b9);  CE(b10, b11);
        // c12..c15 (ranks 13..16) discarded — truncate back to 12
    }

    if (l == 0) {
        int idx[KNN];
        idx[0]=__double2loint(b0);  idx[1]=__double2loint(b1);  idx[2]=__double2loint(b2);
        idx[3]=__double2loint(b3);  idx[4]=__double2loint(b4);  idx[5]=__double2loint(b5);
        idx[6]=__double2loint(b6);  idx[7]=__double2loint(b7);  idx[8]=__double2loint(b8);
        idx[9]=__double2loint(b9);  idx[10]=__double2loint(b10); idx[11]=__double2loint(b11);

        float rx[KNN], ry[KNN], rz[KNN];
        float sx = 0.f, sy = 0.f, sz = 0.f;
#pragma unroll
        for (int s = 0; s < KNN; ++s) {
            int j = idx[s];
            knn[(size_t)iorig * KNN + s] = (unsigned short)j;
            rx[s] = x[(size_t)j * 3 + 0] - xi;
            ry[s] = x[(size_t)j * 3 + 1] - yi;
            rz[s] = x[(size_t)j * 3 + 2] - zi;
            sx += rx[s]; sy += ry[s]; sz += rz[s];
        }
        float mx = sx / 12.0f, my = sy / 12.0f, mz = sz / 12.0f;
        float vx = 0.f, vy = 0.f, vz = 0.f;
#pragma unroll
        for (int s = 0; s < KNN; ++s) {
            float dx = rx[s] - mx, dy = ry[s] - my, dz = rz[s] - mz;
            vx += dx * dx; vy += dy * dy; vz += dz * dz;
        }
        float* rr = relf + (size_t)iorig * 8;
        rr[0] = mx; rr[1] = my; rr[2] = mz;
        rr[3] = sqrtf(vx / 12.0f); rr[4] = sqrtf(vy / 12.0f); rr[5] = sqrtf(vz / 12.0f);
        rr[6] = 0.0f; rr[7] = 0.0f;
    }
}

// ---------------- GEMM + silu (+FiLM): 128x192 tile, 8x12 micro --------------
template <bool LAYER>
__global__ __launch_bounds__(256) void gemm_silu_kernel(
    const float* __restrict__ A0, const float* __restrict__ Agg,
    const float* __restrict__ Rel,
    const float* __restrict__ W, const float* __restrict__ bias,
    const float* __restrict__ gamma, const float* __restrict__ beta,
    float* __restrict__ out)
{
    __shared__ float As[16][132];
    __shared__ float Bs[16][196];
    const int tid = threadIdx.x;
    const int ty = tid >> 4, tx = tid & 15;
    const int m0 = blockIdx.x * 128;

    float acc[8][12] = {};

    const int NCH = LAYER ? 24 : 4;
    for (int ch = 0; ch < NCH; ++ch) {
        const int k0 = ch * 16;
        {
            int row = tid >> 1, koff = (tid & 1) * 8;
            int gi = m0 + row;
            const float* src; int stride, col;
            if (!LAYER)            { src = A0;  stride = 64;  col = k0 + koff; }
            else if (k0 < 192)     { src = A0;  stride = 192; col = k0 + koff; }
            else                   { src = Agg; stride = 192; col = k0 - 192 + koff; }
            float4 v0 = *(const float4*)&src[(size_t)gi * stride + col];
            float4 v1 = *(const float4*)&src[(size_t)gi * stride + col + 4];
            As[koff + 0][row] = v0.x; As[koff + 1][row] = v0.y;
            As[koff + 2][row] = v0.z; As[koff + 3][row] = v0.w;
            As[koff + 4][row] = v1.x; As[koff + 5][row] = v1.y;
            As[koff + 6][row] = v1.z; As[koff + 7][row] = v1.w;
        }
        {
            int k2 = tid >> 4, c = (tid & 15) * 12;
            const float* wr = &W[(size_t)(k0 + k2) * 192 + c];
            float4 w0 = *(const float4*)&wr[0];
            float4 w1 = *(const float4*)&wr[4];
            float4 w2 = *(const float4*)&wr[8];
            *(float4*)&Bs[k2][c + 0] = w0;
            *(float4*)&Bs[k2][c + 4] = w1;
            *(float4*)&Bs[k2][c + 8] = w2;
        }
        __syncthreads();
#pragma unroll
        for (int k = 0; k < 16; ++k) {
            float4 a0 = *(const float4*)&As[k][ty * 8 + 0];
            float4 a1 = *(const float4*)&As[k][ty * 8 + 4];
            float av[8] = {a0.x, a0.y, a0.z, a0.w, a1.x, a1.y, a1.z, a1.w};
            float4 q0 = *(const float4*)&Bs[k][tx * 12 + 0];
            float4 q1 = *(const float4*)&Bs[k][tx * 12 + 4];
            float4 q2 = *(const float4*)&Bs[k][tx * 12 + 8];
            float bv[12] = {q0.x, q0.y, q0.z, q0.w, q1.x, q1.y, q1.z, q1.w,
                            q2.x, q2.y, q2.z, q2.w};
#pragma unroll
            for (int a = 0; a < 8; ++a)
#pragma unroll
                for (int b = 0; b < 12; ++b)
                    acc[a][b] = fmaf(av[a], bv[b], acc[a][b]);
        }
        __syncthreads();
    }

    if (LAYER) {
        {
            int row = tid >> 1, col = (tid & 1) * 4;
            float4 v = *(const float4*)&Rel[(size_t)(m0 + row) * 8 + col];
            As[col + 0][row] = v.x; As[col + 1][row] = v.y;
            As[col + 2][row] = v.z; As[col + 3][row] = v.w;
        }
        {
            int k2 = tid >> 4, c = (tid & 15) * 12;
            if (k2 < 8) {
                int gk = 384 + k2; if (gk > 389) gk = 389;
                const float* wr = &W[(size_t)gk * 192 + c];
                float4 w0 = *(const float4*)&wr[0];
                float4 w1 = *(const float4*)&wr[4];
                float4 w2 = *(const float4*)&wr[8];
                *(float4*)&Bs[k2][c + 0] = w0;
                *(float4*)&Bs[k2][c + 4] = w1;
                *(float4*)&Bs[k2][c + 8] = w2;
            }
        }
        __syncthreads();
#pragma unroll
        for (int k = 0; k < 8; ++k) {
            float4 a0 = *(const float4*)&As[k][ty * 8 + 0];
            float4 a1 = *(const float4*)&As[k][ty * 8 + 4];
            float av[8] = {a0.x, a0.y, a0.z, a0.w, a1.x, a1.y, a1.z, a1.w};
            float4 q0 = *(const float4*)&Bs[k][tx * 12 + 0];
            float4 q1 = *(const float4*)&Bs[k][tx * 12 + 4];
            float4 q2 = *(const float4*)&Bs[k][tx * 12 + 8];
            float bv[12] = {q0.x, q0.y, q0.z, q0.w, q1.x, q1.y, q1.z, q1.w,
                            q2.x, q2.y, q2.z, q2.w};
#pragma unroll
            for (int a = 0; a < 8; ++a)
#pragma unroll
                for (int b = 0; b < 12; ++b)
                    acc[a][b] = fmaf(av[a], bv[b], acc[a][b]);
        }
        __syncthreads();
    }

#pragma unroll
    for (int a = 0; a < 8; ++a) {
        int gi = m0 + ty * 8 + a;
        float res[12];
#pragma unroll
        for (int b = 0; b < 12; ++b) {
            int gc = tx * 12 + b;
            float v = acc[a][b] + bias[gc];
            float s = 1.0f / (1.0f + expf(-v));
            v = v * s;
            if (LAYER) v = v * gamma[gc] + beta[gc];
            res[b] = v;
        }
        float* orow = &out[(size_t)gi * 192 + tx * 12];
        *(float4*)&orow[0] = make_float4(res[0], res[1], res[2], res[3]);
        *(float4*)&orow[4] = make_float4(res[4], res[5], res[6], res[7]);
        *(float4*)&orow[8] = make_float4(res[8], res[9], res[10], res[11]);
    }
}

// ---------------- neighbor aggregation (float4) ------------------------------
__global__ __launch_bounds__(256) void agg_kernel(
    const float4* __restrict__ h4, const unsigned short* __restrict__ knn,
    float4* __restrict__ agg4, int n)
{
    int flat = blockIdx.x * 256 + threadIdx.x;
    int i = flat / 48;
    int c4 = flat - i * 48;
    const unsigned short* kn = knn + (size_t)i * KNN;
    float4 s = make_float4(0.f, 0.f, 0.f, 0.f);
#pragma unroll
    for (int j = 0; j < KNN; ++j) {
        float4 v = h4[(size_t)kn[j] * 48 + c4];
        s.x += v.x; s.y += v.y; s.z += v.z; s.w += v.w;
    }
    const float r = 1.0f / 12.0f;
    agg4[flat] = make_float4(s.x * r, s.y * r, s.z * r, s.w * r);
}

// ---------------- output head ------------------------------------------------
__global__ __launch_bounds__(256) void out_kernel(
    const float4* __restrict__ h4, const float* __restrict__ Wout,
    const float* __restrict__ bout, float* __restrict__ out, int n)
{
    __shared__ float w[576];
    int t = threadIdx.x;
    for (int e = t; e < 576; e += 256) w[e] = Wout[e];
    __syncthreads();
    int i = blockIdx.x * 256 + t;
    float a0 = 0.f, a1 = 0.f, a2 = 0.f;
    for (int k4 = 0; k4 < 48; ++k4) {
        float4 hv = h4[(size_t)i * 48 + k4];
        int k = k4 * 4;
        a0 = fmaf(hv.x, w[k * 3 + 0], a0); a1 = fmaf(hv.x, w[k * 3 + 1], a1); a2 = fmaf(hv.x, w[k * 3 + 2], a2);
        a0 = fmaf(hv.y, w[k * 3 + 3], a0); a1 = fmaf(hv.y, w[k * 3 + 4], a1); a2 = fmaf(hv.y, w[k * 3 + 5], a2);
        a0 = fmaf(hv.z, w[k * 3 + 6], a0); a1 = fmaf(hv.z, w[k * 3 + 7], a1); a2 = fmaf(hv.z, w[k * 3 + 8], a2);
        a0 = fmaf(hv.w, w[k * 3 + 9], a0); a1 = fmaf(hv.w, w[k * 3 + 10], a1); a2 = fmaf(hv.w, w[k * 3 + 11], a2);
    }
    out[(size_t)i * 3 + 0] = (a0 + bout[0]) * 0.01f;
    out[(size_t)i * 3 + 1] = (a1 + bout[1]) * 0.01f;
    out[(size_t)i * 3 + 2] = (a2 + bout[2]) * 0.01f;
}

// ---------------- launch ------------------------------------------------------
extern "C" void kernel_launch(void* const* d_in, const int* in_sizes, int n_in,
                              void* d_out, int out_size, void* d_ws, size_t ws_size,
                              hipStream_t stream)
{
    const float* x    = (const float*)d_in[0];
    const float* z    = (const float*)d_in[1];
    const float* B0   = (const float*)d_in[2];
    const float* B1   = (const float*)d_in[3];
    const float* B2   = (const float*)d_in[4];
    const float* Wp   = (const float*)d_in[5];
    const float* bp   = (const float*)d_in[6];
    const float* Wl   = (const float*)d_in[7];
    const float* bl   = (const float*)d_in[8];
    const float* Wg   = (const float*)d_in[9];
    const float* bg   = (const float*)d_in[10];
    const float* Wb   = (const float*)d_in[11];
    const float* bb   = (const float*)d_in[12];
    const float* Wout = (const float*)d_in[13];
    const float* bout = (const float*)d_in[14];

    int n = in_sizes[0] / 3;  // 32768

    // workspace layout (float offsets)
    float* ws = (float*)d_ws;
    float* bias0  = ws;                    // 192
    float* gammaB = ws + 192;              // 768
    float* betaB  = ws + 960;              // 768
    size_t off = 1728;
    unsigned short* knn = (unsigned short*)(ws + off);  off += (size_t)n * 6;  // 12n u16
    float* relf = ws + off;                off += (size_t)n * 8;
    float* hA   = ws + off;                off += (size_t)n * 192;
    float* hB   = ws + off;                off += (size_t)n * 192;
    float* aggb = ws + off;                off += (size_t)n * 192;

    // grid scratch aliases inside hA (dead before gemm0 writes hA):
    unsigned* bbx     = (unsigned*)hA;              // 8 (6 used)
    unsigned* counts  = bbx + 8;                    // NCELLS
    unsigned* offsA   = counts + NCELLS;            // NCELLS + 1
    unsigned* cursors = offsA + NCELLS + 1;         // NCELLS
    unsigned* bsums   = cursors + NCELLS;           // 256
    size_t gu = 8 + (size_t)NCELLS * 3 + 1 + 256;
    gu = (gu + 3) & ~(size_t)3;                     // 16B align for float4
    float4* sorted = (float4*)((unsigned*)hA + gu); // n float4
    float* pe = hB;

    init_bbox_kernel<<<1, 64, 0, stream>>>(bbx);
    hipMemsetAsync(counts, 0, (size_t)NCELLS * 4, stream);
    prep_kernel<<<n / 256, 256, 0, stream>>>(x, B0, B1, B2, pe, n);
    precompute_kernel<<<1, 256, 0, stream>>>(z, Wp, bp, Wg, bg, Wb, bb,
                                             bias0, gammaB, betaB);
    bbox_kernel<<<n / 256, 256, 0, stream>>>(x, bbx, n);
    hist_kernel<<<n / 256, 256, 0, stream>>>(x, bbx, counts, n);
    scan1_kernel<<<NCELLS / 1024, 256, 0, stream>>>(counts, offsA, bsums);
    scan2_kernel<<<1, 256, 0, stream>>>(bsums);
    scan3_kernel<<<NCELLS / 1024, 256, 0, stream>>>(offsA, bsums, cursors, n);
    scatter_kernel<<<n / 256, 256, 0, stream>>>(x, bbx, cursors, sorted, n);
    knn_grid_kernel<<<n / 16, 256, 0, stream>>>(sorted, offsA, bbx, x, knn, relf, n);

    gemm_silu_kernel<false><<<n / 128, 256, 0, stream>>>(
        pe, nullptr, nullptr, Wp, bias0, nullptr, nullptr, hA);

    float* hcur = hA;
    float* hnxt = hB;
    for (int li = 0; li < 4; ++li) {
        agg_kernel<<<(size_t)n * 48 / 256, 256, 0, stream>>>(
            (const float4*)hcur, knn, (float4*)aggb, n);
        gemm_silu_kernel<true><<<n / 128, 256, 0, stream>>>(
            hcur, aggb, relf,
            Wl + (size_t)li * 390 * 192, bl + (size_t)li * 192,
            gammaB + (size_t)li * 192, betaB + (size_t)li * 192, hnxt);
        float* t = hcur; hcur = hnxt; hnxt = t;
    }

    out_kernel<<<n / 256, 256, 0, stream>>>((const float4*)hcur, Wout, bout,
                                            (float*)d_out, n);
}